// Round 1
// 2152.725 us; speedup vs baseline: 1.0075x; 1.0075x over previous
//
#include <hip/hip_runtime.h>
#include <math.h>

#define TS 256      // seq len
#define BS 32       // batch
#define NF 1024     // features
#define NH 16       // heads
#define HD 64       // head dim
#define PD 1024     // packed dim
#define FFD 4096    // feedforward
#define NLAYER 6
#define ROWS (TS*BS)   // 8192 tokens
#define LNEPS 1e-5f

typedef unsigned int u32;
typedef __attribute__((ext_vector_type(8))) short bf16x8;   // 8 bf16 = 4 VGPRs
typedef __attribute__((ext_vector_type(4))) float f32x4;

__device__ __forceinline__ unsigned short f2bf(float f) {
    u32 u = __builtin_bit_cast(u32, f);
    u32 r = (u + 0x7fffu + ((u >> 16) & 1u)) >> 16;   // RNE
    return (unsigned short)r;
}

// async global->LDS 16B copy (dest must be wave-uniform base + lane*16)
__device__ __forceinline__ void async16(const void* g, void* l) {
    __builtin_amdgcn_global_load_lds(
        (const __attribute__((address_space(1))) u32*)g,
        (__attribute__((address_space(3))) u32*)l, 16, 0, 0);
}

// ---------------------------------------------------------------------------
// LayerNorm: one block (256 threads) per row of N=1024. BF16OUT: emit bf16.
// ---------------------------------------------------------------------------
template <int BF16OUT>
__global__ __launch_bounds__(256)
void ln_kernel(const float* __restrict__ x, void* __restrict__ y,
               const float* __restrict__ g, const float* __restrict__ b) {
    int row = blockIdx.x;
    int tid = threadIdx.x;
    const float4* xr = (const float4*)(x + (size_t)row * NF);
    float4 v = xr[tid];
    float s  = v.x + v.y + v.z + v.w;
    float ss = v.x*v.x + v.y*v.y + v.z*v.z + v.w*v.w;
    #pragma unroll
    for (int off = 32; off > 0; off >>= 1) {
        s  += __shfl_down(s,  off);
        ss += __shfl_down(ss, off);
    }
    __shared__ float ws[4], wss[4];
    int wid = tid >> 6, lane = tid & 63;
    if (lane == 0) { ws[wid] = s; wss[wid] = ss; }
    __syncthreads();
    float sum   = ws[0] + ws[1] + ws[2] + ws[3];
    float sumsq = wss[0] + wss[1] + wss[2] + wss[3];
    float mean = sum * (1.0f / NF);
    float var  = sumsq * (1.0f / NF) - mean * mean;
    float rstd = rsqrtf(var + LNEPS);
    float4 gv = ((const float4*)g)[tid];
    float4 bv = ((const float4*)b)[tid];
    float4 o;
    o.x = (v.x - mean) * rstd * gv.x + bv.x;
    o.y = (v.y - mean) * rstd * gv.y + bv.y;
    o.z = (v.z - mean) * rstd * gv.z + bv.z;
    o.w = (v.w - mean) * rstd * gv.w + bv.w;
    if (BF16OUT) {
        ushort4 ov;
        ov.x = f2bf(o.x); ov.y = f2bf(o.y); ov.z = f2bf(o.z); ov.w = f2bf(o.w);
        ((ushort4*)((unsigned short*)y + (size_t)row * NF))[tid] = ov;
    } else {
        ((float4*)((float*)y + (size_t)row * NF))[tid] = o;
    }
}

// ---------------------------------------------------------------------------
// fp32 -> bf16 convert, 4 arrays in one launch (blockIdx.y selects array)
// ---------------------------------------------------------------------------
__global__ __launch_bounds__(256)
void f2bf4_kernel(const float* __restrict__ s0, const float* __restrict__ s1,
                  const float* __restrict__ s2, const float* __restrict__ s3,
                  unsigned short* __restrict__ d0, unsigned short* __restrict__ d1,
                  unsigned short* __restrict__ d2, unsigned short* __restrict__ d3,
                  int n0, int n1, int n2, int n3) {
    const float* s; unsigned short* d; int n;
    switch (blockIdx.y) {
        case 0: s = s0; d = d0; n = n0; break;
        case 1: s = s1; d = d1; n = n1; break;
        case 2: s = s2; d = d2; n = n2; break;
        default: s = s3; d = d3; n = n3; break;
    }
    int i = (blockIdx.x * 256 + threadIdx.x) * 4;
    if (i >= n) return;
    float4 v = *(const float4*)(s + i);
    ushort4 o;
    o.x = f2bf(v.x); o.y = f2bf(v.y); o.z = f2bf(v.z); o.w = f2bf(v.w);
    *(ushort4*)(d + i) = o;
}

// ---------------------------------------------------------------------------
// bf16 MFMA GEMM (NT): C[M,N] = A[M,K] * B[N,K]^T + bias[N]
// 128x128 tile, BK=64, 256 threads (4 waves, 2x2 quadrants of 64x64).
// Kept for the N=1024 GEMMs (Wo, W2) where a 256^2 grid would underfill.
// MODE: 0 = fp32 row-major out (+optional resid), 1 = bf16 relu out,
//       2 = bf16 out in [3][B][H][T][HD] (QKV transpose, q*0.125)
// ---------------------------------------------------------------------------
template <int MODE, int RESID>
__global__ __launch_bounds__(256)
void gemm_mfma(const unsigned short* __restrict__ A, const unsigned short* __restrict__ B,
               const float* __restrict__ bias, const float* __restrict__ resid,
               void* __restrict__ Cout, int M, int N, int K) {
    __shared__ __align__(16) unsigned short sA0[128 * 64];
    __shared__ __align__(16) unsigned short sA1[128 * 64];
    __shared__ __align__(16) unsigned short sB0[128 * 64];
    __shared__ __align__(16) unsigned short sB1[128 * 64];
    int tid = threadIdx.x;

    int Nb = N >> 7;
    int bid = blockIdx.x;
    int group = bid / (8 * Nb);
    int rem = bid - group * (8 * Nb);
    int m0 = (group * 8 + rem / Nb) * 128;
    int n0 = (rem % Nb) * 128;

    int rB = tid >> 3;
    int c0 = (tid & 7) ^ (rB & 7);
    const unsigned short* gA[4];
    const unsigned short* gB[4];
    #pragma unroll
    for (int it = 0; it < 4; it++) {
        gA[it] = A + (size_t)(m0 + rB + 32 * it) * K + c0 * 8;
        gB[it] = B + (size_t)(n0 + rB + 32 * it) * K + c0 * 8;
    }

    int wid = tid >> 6, lane = tid & 63;
    int wm = wid >> 1, wn = wid & 1;
    int quad = lane >> 4, rl = lane & 15;

    int aoff[2][4], boff[2][4];
    #pragma unroll
    for (int ks = 0; ks < 2; ks++)
        #pragma unroll
        for (int t = 0; t < 4; t++) {
            int r = wm * 64 + t * 16 + rl;
            aoff[ks][t] = r * 64 + ((ks * 4 + quad) ^ (r & 7)) * 8;
            int rn = wn * 64 + t * 16 + rl;
            boff[ks][t] = rn * 64 + ((ks * 4 + quad) ^ (rn & 7)) * 8;
        }

    f32x4 acc[4][4] = {};

    auto stage = [&](int t, unsigned short* dA, unsigned short* dB) {
        int kt = t << 6;
        #pragma unroll
        for (int it = 0; it < 4; it++) {
            async16(gA[it] + kt, dA + (tid + 256 * it) * 8);
            async16(gB[it] + kt, dB + (tid + 256 * it) * 8);
        }
    };
    auto compute = [&](const unsigned short* pA, const unsigned short* pB) {
        #pragma unroll
        for (int ks = 0; ks < 2; ks++) {
            bf16x8 a[4], b[4];
            #pragma unroll
            for (int t = 0; t < 4; t++) {
                a[t] = *(const bf16x8*)(pA + aoff[ks][t]);
                b[t] = *(const bf16x8*)(pB + boff[ks][t]);
            }
            #pragma unroll
            for (int i = 0; i < 4; i++)
                #pragma unroll
                for (int j = 0; j < 4; j++)
                    acc[i][j] = __builtin_amdgcn_mfma_f32_16x16x32_bf16(a[i], b[j], acc[i][j], 0, 0, 0);
        }
    };

    int nT = K >> 6;
    stage(0, sA0, sB0);
    for (int t = 0; t < nT; t += 2) {
        __syncthreads();
        stage(t + 1, sA1, sB1);
        compute(sA0, sB0);
        __syncthreads();
        if (t + 2 < nT) stage(t + 2, sA0, sB0);
        compute(sA1, sB1);
    }

    float bvv[4];
    #pragma unroll
    for (int nt = 0; nt < 4; nt++) bvv[nt] = bias[n0 + wn * 64 + nt * 16 + rl];
    #pragma unroll
    for (int mt = 0; mt < 4; mt++) {
        #pragma unroll
        for (int nt = 0; nt < 4; nt++) {
            #pragma unroll
            for (int r = 0; r < 4; r++) {
                int row = m0 + wm * 64 + mt * 16 + quad * 4 + r;
                int col = n0 + wn * 64 + nt * 16 + rl;
                float v = acc[mt][nt][r] + bvv[nt];
                if (MODE == 0) {
                    if (RESID) v += resid[(size_t)row * N + col];
                    ((float*)Cout)[(size_t)row * N + col] = v;
                } else if (MODE == 1) {
                    v = fmaxf(v, 0.0f);
                    ((unsigned short*)Cout)[(size_t)row * N + col] = f2bf(v);
                } else {
                    int t = row >> 5, bb = row & 31;
                    int s = col >> 10, hh = (col >> 6) & 15, d = col & 63;
                    if (s == 0) v *= 0.125f;
                    ((unsigned short*)Cout)[((((size_t)s * BS + bb) * NH + hh) * TS + t) * HD + d] = f2bf(v);
                }
            }
        }
    }
}

// ---------------------------------------------------------------------------
// 256x256 8-phase bf16 MFMA GEMM (NT): C = A[M,K] * B[N,K]^T + bias[N].
// 512 threads = 8 waves (2M x 4N), wave tile 128x64 INTERLEAVED over M
// (fragment mi -> rows mi*32 + wm*16): this confines all ds_reads of LDS
// A-half0 (rows 0..127) to phase 0, A-half1 to phase 2, each B-half to
// phases 0-1 -- which makes per-phase half-tile staging race-free:
//   phase0: read a(qm0)+b(qn0) (12x b128), stage B1(t+1)->other buf, MFMA(qm0,qn0)
//   phase1: read b(qn1) (4x),              stage A0(t+2)->cur buf,   MFMA(qm0,qn1)
//   phase2: read a(qm1) (8x),              stage B0(t+2)->cur buf,   MFMA(qm1,qn1)
//   phase3: (no reads),                    stage A1(t+2)->cur buf,   MFMA(qm1,qn0)
//           then s_waitcnt vmcnt(6)  (counted: 3 half-tiles stay in flight)
// A region staged at phase p was last ds_read at phase <= p-1 and all waves'
// reads are retired (own lgkmcnt(0) precedes MFMA, precedes end barrier)
// before any wave issues the stage. Tile t+1 is guaranteed landed by the
// vmcnt(6) at the end of tile t (tail: vmcnt(0) once stages stop).
// LDS 128 KiB (2 x [256][64] x A,B), chunk swizzle p ^= (row&7) via
// pre-swizzled global source. Never drains vmcnt to 0 mid-loop.
// ---------------------------------------------------------------------------
template <int MODE>
__global__ __launch_bounds__(512, 2)
void gemm256(const unsigned short* __restrict__ A, const unsigned short* __restrict__ B,
             const float* __restrict__ bias, void* __restrict__ Cout,
             int M, int N, int K) {
    __shared__ __align__(16) unsigned short sA[2 * 256 * 64];
    __shared__ __align__(16) unsigned short sB[2 * 256 * 64];
    int tid = threadIdx.x;
    (void)M;

    // XCD-aware swizzle (grid % 8 == 0 for all our shapes) + grouped (8 m/group, n fast)
    int Nb = N >> 8;
    int nwg = gridDim.x;
    int bid = blockIdx.x;
    int wgid = (bid & 7) * (nwg >> 3) + (bid >> 3);
    int gsz = 8 * Nb;
    int group = wgid / gsz, rem = wgid - group * gsz;
    int m0 = (group * 8 + rem / Nb) << 8;
    int n0 = (rem - (rem / Nb) * Nb) << 8;

    // staging: per instr, 512 thr x 16B = 64 rows; LDS dest linear (tid*16B),
    // source chunk pre-swizzled so stored chunk p holds data chunk p^(row&7)
    int rr = tid >> 3;                       // row within 64-row slab
    int cd = (tid & 7) ^ (rr & 7);           // swizzled source chunk
    const unsigned short* gA0 = A + (size_t)(m0 + rr) * K + cd * 8;
    const unsigned short* gB0 = B + (size_t)(n0 + rr) * K + cd * 8;
    size_t sK64 = (size_t)64 * K;

    auto stgA = [&](int buf, int h, int kt) {     // half h (128 rows) of A k-tile
        unsigned short* d = sA + buf * 16384 + h * 8192 + tid * 8;
        const unsigned short* g = gA0 + (size_t)(h * 2) * sK64 + kt;
        async16(g, d);
        async16(g + sK64, d + 4096);
    };
    auto stgB = [&](int buf, int h, int kt) {
        unsigned short* d = sB + buf * 16384 + h * 8192 + tid * 8;
        const unsigned short* g = gB0 + (size_t)(h * 2) * sK64 + kt;
        async16(g, d);
        async16(g + sK64, d + 4096);
    };

    int wid = tid >> 6, lane = tid & 63;
    int wm = wid >> 2, wn = wid & 3;
    int quad = lane >> 4, rl = lane & 15;

    // a frag (j,ks) at qm: LDS row = qm*128 + j*32 + wm*16 + rl  (row&7 == rl&7)
    // b frag (nt,ks):      LDS row = wn*64 + nt*16 + rl
    int aoff[4][2], boff[4][2];
    #pragma unroll
    for (int j = 0; j < 4; ++j)
        #pragma unroll
        for (int ks = 0; ks < 2; ++ks) {
            int r = j * 32 + wm * 16 + rl;
            aoff[j][ks] = r * 64 + (((ks * 4 + quad) ^ (r & 7)) << 3);
            int rn = wn * 64 + j * 16 + rl;
            boff[j][ks] = rn * 64 + (((ks * 4 + quad) ^ (rn & 7)) << 3);
        }

    f32x4 acc[8][4] = {};
    int nT = K >> 6;

    // prologue: tile0 complete + first 3 halves of tile1; 3 halves stay in flight
    stgA(0, 0, 0); stgB(0, 0, 0); stgA(0, 1, 0); stgB(0, 1, 0);
    if (nT > 1) {
        stgA(1, 0, 64); stgB(1, 0, 64); stgA(1, 1, 64);
        asm volatile("s_waitcnt vmcnt(6)" ::: "memory");
    } else {
        asm volatile("s_waitcnt vmcnt(0)" ::: "memory");
    }
    __builtin_amdgcn_s_barrier();
    __builtin_amdgcn_sched_barrier(0);

    bf16x8 a[4][2], b[4][2];
    for (int t = 0; t < nT; ++t) {
        int buf = t & 1;
        const unsigned short* pA = sA + buf * 16384;
        const unsigned short* pB = sB + buf * 16384;
        int kt1 = (t + 1) << 6, kt2 = (t + 2) << 6;
        int s1 = (t + 1) < nT, s2 = (t + 2) < nT;

        // ---- phase 0: MFMA (qm0, qn0) ----
        #pragma unroll
        for (int j = 0; j < 4; ++j) {
            a[j][0] = *(const bf16x8*)(pA + aoff[j][0]);
            a[j][1] = *(const bf16x8*)(pA + aoff[j][1]);
        }
        #pragma unroll
        for (int i = 0; i < 2; ++i) {
            b[i][0] = *(const bf16x8*)(pB + boff[i][0]);
            b[i][1] = *(const bf16x8*)(pB + boff[i][1]);
        }
        if (s1) stgB(buf ^ 1, 1, kt1);
        asm volatile("s_waitcnt lgkmcnt(8)" ::: "memory");
        __builtin_amdgcn_s_barrier();
        asm volatile("s_waitcnt lgkmcnt(0)" ::: "memory");
        __builtin_amdgcn_sched_barrier(0);
        __builtin_amdgcn_s_setprio(1);
        #pragma unroll
        for (int j = 0; j < 4; ++j)
            #pragma unroll
            for (int i = 0; i < 2; ++i) {
                acc[j][i] = __builtin_amdgcn_mfma_f32_16x16x32_bf16(a[j][0], b[i][0], acc[j][i], 0, 0, 0);
                acc[j][i] = __builtin_amdgcn_mfma_f32_16x16x32_bf16(a[j][1], b[i][1], acc[j][i], 0, 0, 0);
            }
        __builtin_amdgcn_s_setprio(0);
        __builtin_amdgcn_s_barrier();
        __builtin_amdgcn_sched_barrier(0);

        // ---- phase 1: MFMA (qm0, qn1) ----
        #pragma unroll
        for (int i = 2; i < 4; ++i) {
            b[i][0] = *(const bf16x8*)(pB + boff[i][0]);
            b[i][1] = *(const bf16x8*)(pB + boff[i][1]);
        }
        if (s2) stgA(buf, 0, kt2);
        __builtin_amdgcn_s_barrier();
        asm volatile("s_waitcnt lgkmcnt(0)" ::: "memory");
        __builtin_amdgcn_sched_barrier(0);
        __builtin_amdgcn_s_setprio(1);
        #pragma unroll
        for (int j = 0; j < 4; ++j)
            #pragma unroll
            for (int i = 2; i < 4; ++i) {
                acc[j][i] = __builtin_amdgcn_mfma_f32_16x16x32_bf16(a[j][0], b[i][0], acc[j][i], 0, 0, 0);
                acc[j][i] = __builtin_amdgcn_mfma_f32_16x16x32_bf16(a[j][1], b[i][1], acc[j][i], 0, 0, 0);
            }
        __builtin_amdgcn_s_setprio(0);
        __builtin_amdgcn_s_barrier();
        __builtin_amdgcn_sched_barrier(0);

        // ---- phase 2: MFMA (qm1, qn1), reuse a[] registers for qm=1 ----
        #pragma unroll
        for (int j = 0; j < 4; ++j) {
            a[j][0] = *(const bf16x8*)(pA + 8192 + aoff[j][0]);
            a[j][1] = *(const bf16x8*)(pA + 8192 + aoff[j][1]);
        }
        if (s2) stgB(buf, 0, kt2);
        __builtin_amdgcn_s_barrier();
        asm volatile("s_waitcnt lgkmcnt(0)" ::: "memory");
        __builtin_amdgcn_sched_barrier(0);
        __builtin_amdgcn_s_setprio(1);
        #pragma unroll
        for (int j = 0; j < 4; ++j)
            #pragma unroll
            for (int i = 2; i < 4; ++i) {
                acc[4 + j][i] = __builtin_amdgcn_mfma_f32_16x16x32_bf16(a[j][0], b[i][0], acc[4 + j][i], 0, 0, 0);
                acc[4 + j][i] = __builtin_amdgcn_mfma_f32_16x16x32_bf16(a[j][1], b[i][1], acc[4 + j][i], 0, 0, 0);
            }
        __builtin_amdgcn_s_setprio(0);
        __builtin_amdgcn_s_barrier();
        __builtin_amdgcn_sched_barrier(0);

        // ---- phase 3: MFMA (qm1, qn0), no new ds_reads ----
        if (s2) stgA(buf, 1, kt2);
        __builtin_amdgcn_s_barrier();
        asm volatile("s_waitcnt lgkmcnt(0)" ::: "memory");
        __builtin_amdgcn_sched_barrier(0);
        __builtin_amdgcn_s_setprio(1);
        #pragma unroll
        for (int j = 0; j < 4; ++j)
            #pragma unroll
            for (int i = 0; i < 2; ++i) {
                acc[4 + j][i] = __builtin_amdgcn_mfma_f32_16x16x32_bf16(a[j][0], b[i][0], acc[4 + j][i], 0, 0, 0);
                acc[4 + j][i] = __builtin_amdgcn_mfma_f32_16x16x32_bf16(a[j][1], b[i][1], acc[4 + j][i], 0, 0, 0);
            }
        __builtin_amdgcn_s_setprio(0);
        if (s2) asm volatile("s_waitcnt vmcnt(6)" ::: "memory");
        else    asm volatile("s_waitcnt vmcnt(0)" ::: "memory");
        __builtin_amdgcn_s_barrier();
        __builtin_amdgcn_sched_barrier(0);
    }

    // epilogue: C/D col = lane&15, row = quad*4 + reg; frag mi -> rows mi*32+wm*16
    float bvv[4];
    #pragma unroll
    for (int ni = 0; ni < 4; ++ni) bvv[ni] = bias[n0 + wn * 64 + ni * 16 + rl];
    #pragma unroll
    for (int mi = 0; mi < 8; ++mi) {
        #pragma unroll
        for (int ni = 0; ni < 4; ++ni) {
            #pragma unroll
            for (int r = 0; r < 4; ++r) {
                int row = m0 + mi * 32 + wm * 16 + quad * 4 + r;
                int col = n0 + wn * 64 + ni * 16 + rl;
                float v = acc[mi][ni][r] + bvv[ni];
                if (MODE == 1) {
                    v = fmaxf(v, 0.0f);
                    ((unsigned short*)Cout)[(size_t)row * N + col] = f2bf(v);
                } else {
                    int tt = row >> 5, bb = row & 31;
                    int s = col >> 10, hh = (col >> 6) & 15, d = col & 63;
                    if (s == 0) v *= 0.125f;
                    ((unsigned short*)Cout)[((((size_t)s * BS + bb) * NH + hh) * TS + tt) * HD + d] = f2bf(v);
                }
            }
        }
    }
}

// ---------------------------------------------------------------------------
// MFMA attention. qkvT: bf16 [3][B][H][T][HD] (q pre-scaled by 1/8).
// ---------------------------------------------------------------------------
__global__ __launch_bounds__(256, 2)
void attn_mfma(const unsigned short* __restrict__ qkvT, const float* __restrict__ mask,
               unsigned short* __restrict__ o) {
    int bx = blockIdx.x;
    int bh = bx >> 1, half = bx & 1;
    int b = bh >> 4, h = bh & 15;
    const unsigned short* qB = qkvT + (size_t)bh * TS * HD;
    const unsigned short* kB = qB + (size_t)BS * NH * TS * HD;
    const unsigned short* vB = kB + (size_t)BS * NH * TS * HD;
    int tid = threadIdx.x, lane = tid & 63, wid = tid >> 6;
    int quad = lane >> 4, rl = lane & 15;
    int tbase = half * 128 + wid * 32;

    __shared__ __align__(16) unsigned short sKV[18432];   // K [256][72] then Vt [64][264]
    __shared__ __align__(16) unsigned short sP[4][1280];  // per-wave P scratch [32][40]

    #pragma unroll
    for (int it = 0; it < 8; it++) {
        int idx = it * 256 + tid, rrow = idx >> 3, ch = idx & 7;
        *(uint4*)(sKV + rrow * 72 + ch * 8) = *(const uint4*)(kB + (size_t)rrow * 64 + ch * 8);
    }

    bf16x8 qf[2][2];
    #pragma unroll
    for (int mt = 0; mt < 2; mt++)
        #pragma unroll
        for (int ks = 0; ks < 2; ks++)
            qf[mt][ks] = *(const bf16x8*)(qB + (size_t)(tbase + mt * 16 + rl) * 64 + ks * 32 + quad * 8);

    __syncthreads();

    f32x4 S[2][16] = {};
    #pragma unroll
    for (int nt = 0; nt < 16; nt++) {
        bf16x8 k0 = *(const bf16x8*)(sKV + (nt * 16 + rl) * 72 + quad * 8);
        bf16x8 k1 = *(const bf16x8*)(sKV + (nt * 16 + rl) * 72 + 32 + quad * 8);
        #pragma unroll
        for (int mt = 0; mt < 2; mt++) {
            S[mt][nt] = __builtin_amdgcn_mfma_f32_16x16x32_bf16(qf[mt][0], k0, S[mt][nt], 0, 0, 0);
            S[mt][nt] = __builtin_amdgcn_mfma_f32_16x16x32_bf16(qf[mt][1], k1, S[mt][nt], 0, 0, 0);
        }
    }

    float linv[2][4];
    #pragma unroll
    for (int mt = 0; mt < 2; mt++) {
        #pragma unroll
        for (int r = 0; r < 4; r++) {
            int tg = tbase + mt * 16 + quad * 4 + r;
            const float* mrow = mask + (size_t)tg * TS + rl;
            float mx = -3.0e38f;
            #pragma unroll
            for (int nt = 0; nt < 16; nt++) {
                S[mt][nt][r] += mrow[nt * 16];
                mx = fmaxf(mx, S[mt][nt][r]);
            }
            mx = fmaxf(mx, __shfl_xor(mx, 1));
            mx = fmaxf(mx, __shfl_xor(mx, 2));
            mx = fmaxf(mx, __shfl_xor(mx, 4));
            mx = fmaxf(mx, __shfl_xor(mx, 8));
            float sum = 0.0f;
            #pragma unroll
            for (int nt = 0; nt < 16; nt++) {
                float p = __expf(S[mt][nt][r] - mx);
                S[mt][nt][r] = p;
                sum += p;
            }
            sum += __shfl_xor(sum, 1);
            sum += __shfl_xor(sum, 2);
            sum += __shfl_xor(sum, 4);
            sum += __shfl_xor(sum, 8);
            linv[mt][r] = 1.0f / sum;
        }
    }

    __syncthreads();
    #pragma unroll
    for (int it = 0; it < 8; it++) {
        int idx = it * 256 + tid, srow = idx >> 3, dc = idx & 7;
        bf16x8 vv = *(const bf16x8*)(vB + (size_t)srow * 64 + dc * 8);
        #pragma unroll
        for (int j = 0; j < 8; j++)
            sKV[(dc * 8 + j) * 264 + srow] = (unsigned short)vv[j];
    }
    __syncthreads();

    f32x4 O[2][4] = {};
    unsigned short* myP = sP[wid];
    #pragma unroll
    for (int sc = 0; sc < 8; sc++) {
        #pragma unroll
        for (int mt = 0; mt < 2; mt++)
            #pragma unroll
            for (int hi = 0; hi < 2; hi++)
                #pragma unroll
                for (int r = 0; r < 4; r++)
                    myP[(mt * 16 + quad * 4 + r) * 40 + hi * 16 + rl] = f2bf(S[mt][2 * sc + hi][r]);
        bf16x8 pa[2], vf[4];
        #pragma unroll
        for (int mt = 0; mt < 2; mt++)
            pa[mt] = *(const bf16x8*)(myP + (mt * 16 + rl) * 40 + quad * 8);
        #pragma unroll
        for (int nd = 0; nd < 4; nd++)
            vf[nd] = *(const bf16x8*)(sKV + (nd * 16 + rl) * 264 + sc * 32 + quad * 8);
        #pragma unroll
        for (int mt = 0; mt < 2; mt++)
            #pragma unroll
            for (int nd = 0; nd < 4; nd++)
                O[mt][nd] = __builtin_amdgcn_mfma_f32_16x16x32_bf16(pa[mt], vf[nd], O[mt][nd], 0, 0, 0);
    }

    #pragma unroll
    for (int mt = 0; mt < 2; mt++)
        #pragma unroll
        for (int nd = 0; nd < 4; nd++)
            #pragma unroll
            for (int r = 0; r < 4; r++) {
                int tg = tbase + mt * 16 + quad * 4 + r;
                int d = nd * 16 + rl;
                o[(size_t)(tg * BS + b) * PD + h * HD + d] = f2bf(O[mt][nd][r] * linv[mt][r]);
            }
}

// ---------------------------------------------------------------------------
extern "C" void kernel_launch(void* const* d_in, const int* in_sizes, int n_in,
                              void* d_out, int out_size, void* d_ws, size_t ws_size,
                              hipStream_t stream) {
    const float* src  = (const float*)d_in[0];
    const float* mask = (const float*)d_in[1];
    const float* Wqkv = (const float*)d_in[2];
    const float* bqkv = (const float*)d_in[3];
    const float* Wo   = (const float*)d_in[4];
    const float* bo   = (const float*)d_in[5];
    const float* ln1g = (const float*)d_in[6];
    const float* ln1b = (const float*)d_in[7];
    const float* ln2g = (const float*)d_in[8];
    const float* ln2b = (const float*)d_in[9];
    const float* W1   = (const float*)d_in[10];
    const float* b1   = (const float*)d_in[11];
    const float* W2   = (const float*)d_in[12];
    const float* b2   = (const float*)d_in[13];
    const float* lnfg = (const float*)d_in[14];
    const float* lnfb = (const float*)d_in[15];

    float* x = (float*)d_out;
    char* ws = (char*)d_ws;
    unsigned short* qkvT = (unsigned short*)ws;
    unsigned short* ff   = (unsigned short*)ws;
    unsigned short* h    = (unsigned short*)(ws + 67108864);
    unsigned short* o    = (unsigned short*)(ws + 83886080);
    unsigned short* wbuf = (unsigned short*)(ws + 100663296);
    unsigned short* wq = wbuf;
    unsigned short* wo = wbuf + 3145728;
    unsigned short* w1 = wbuf + 4194304;
    unsigned short* w2 = wbuf + 8388608;

    hipMemcpyAsync(x, src, (size_t)ROWS * NF * 4, hipMemcpyDeviceToDevice, stream);

    for (int l = 0; l < NLAYER; l++) {
        const float* wqkv_l = Wqkv + (size_t)l * 3 * PD * NF;
        const float* bqkv_l = bqkv + (size_t)l * 3 * PD;
        const float* wo_l   = Wo + (size_t)l * NF * PD;
        const float* bo_l   = bo + (size_t)l * NF;
        const float* w1_l   = W1 + (size_t)l * FFD * NF;
        const float* b1_l   = b1 + (size_t)l * FFD;
        const float* w2_l   = W2 + (size_t)l * NF * FFD;
        const float* b2_l   = b2 + (size_t)l * NF;

        f2bf4_kernel<<<dim3(4096, 4), 256, 0, stream>>>(
            wqkv_l, wo_l, w1_l, w2_l, wq, wo, w1, w2,
            3 * PD * NF, NF * PD, FFD * NF, NF * FFD);
        ln_kernel<1><<<ROWS, 256, 0, stream>>>(x, h, ln1g + (size_t)l * NF, ln1b + (size_t)l * NF);
        // qkvT = (h @ Wqkv^T + bqkv) -> bf16 [3][B][H][T][HD]  (256^2 8-phase)
        gemm256<2><<<(ROWS / 256) * (3 * PD / 256), 512, 0, stream>>>(
            h, wq, bqkv_l, qkvT, ROWS, 3 * PD, NF);
        attn_mfma<<<BS * NH * 2, 256, 0, stream>>>(qkvT, mask, o);
        // x = x + o @ Wo^T + bo   (N=1024 -> keep 128^2 kernel)
        gemm_mfma<0, 1><<<(ROWS / 128) * (NF / 128), 256, 0, stream>>>(
            o, wo, bo_l, x, x, ROWS, NF, PD);
        ln_kernel<1><<<ROWS, 256, 0, stream>>>(x, h, ln2g + (size_t)l * NF, ln2b + (size_t)l * NF);
        // ff = bf16(relu(h @ W1^T + b1))  (256^2 8-phase)
        gemm256<1><<<(ROWS / 256) * (FFD / 256), 512, 0, stream>>>(
            h, w1, b1_l, ff, ROWS, FFD, NF);
        // x = x + ff @ W2^T + b2  (N=1024 -> keep 128^2 kernel)
        gemm_mfma<0, 1><<<(ROWS / 128) * (NF / 128), 256, 0, stream>>>(
            ff, w2, b2_l, x, x, ROWS, NF, FFD);
    }
    ln_kernel<0><<<ROWS, 256, 0, stream>>>(x, x, lnfg, lnfb);
}